// Round 7
// baseline (193.086 us; speedup 1.0000x reference)
//
#include <hip/hip_runtime.h>
#include <math.h>

// Bucketed rank/cumsum (round 7): round-6 pipeline (fused scan+reduce, shuffle
// k_final — both green) with k_main rewritten as a WAVE-COOPERATIVE broadcast
// scan: each lane loads one window element (coalesced), 64 shfl-broadcast steps
// give all lanes all elements -> the O(g^2) within-bucket rank scan becomes
// pure VALU with zero load-latency exposure (round-5/6 per-lane load versions
// were latency-bound at 46/71 us; VALU floor is ~4 us).
// In-wave shuffles only: deterministic, replay-safe (no LDS staging, no new
// sync — the machinery that broke rounds 2/4 is not used).
//   key = float bits of time (positive floats order monotonically).
//   bucket = key >> 14 -> 2^17 buckets covers every positive float.
//   k_hist: R=8 replicas -> ~32-way same-address contention; seq[i] = atomicAdd
//     return = slot within (r,bucket). Suffix scans over buckets give
//     (count above, exp-sum above); within-bucket order resolved exactly in
//     k_main (order-invariant). Tie-break (key desc, idx asc) = top_k stability.

#define BSHIFT 14
#define NBUCK (1 << 17)           // 131072; max positive-float key>>14 = 130047
#define SCAN_BLK 1024
#define NPART (NBUCK / SCAN_BLK)  // 128
#define RMAX 8

__global__ void k_hist(const float* __restrict__ yt0, const float* __restrict__ yp0,
                       int n, int rmask,
                       unsigned* __restrict__ count, float* __restrict__ expsum,
                       unsigned* __restrict__ seq) {
  int i = blockIdx.x * blockDim.x + threadIdx.x;
  if (i >= n) return;
  int r = blockIdx.x & rmask;
  unsigned key = __float_as_uint(yt0[2 * i]);
  unsigned b = key >> BSHIFT;
  seq[i] = atomicAdd(&count[(size_t)r * NBUCK + b], 1u);
  atomicAdd(&expsum[(size_t)r * NBUCK + b], expf(yp0[i]));
}

// Fold replicas (countTot/expTot/offArr) AND produce per-part suffix partials.
__global__ void k_scan_reduce(const unsigned* __restrict__ count, const float* __restrict__ expsum,
                              int nrep,
                              unsigned* __restrict__ countTot, float* __restrict__ expTot,
                              unsigned* __restrict__ offArr,
                              unsigned* __restrict__ cntPart, float* __restrict__ expPart) {
  __shared__ unsigned sc[SCAN_BLK];
  __shared__ float sf[SCAN_BLK];
  int t = threadIdx.x, g = blockIdx.x;
  int b = NBUCK - 1 - (g * SCAN_BLK + t);  // reversed order -> suffix scan
  unsigned tot = 0;
  float ftot = 0.f;
  for (int r = 0; r < nrep; ++r) {
    offArr[(size_t)r * NBUCK + b] = tot;
    tot += count[(size_t)r * NBUCK + b];
    ftot += expsum[(size_t)r * NBUCK + b];
  }
  countTot[b] = tot;
  expTot[b] = ftot;
  sc[t] = tot;
  sf[t] = ftot;
  __syncthreads();
  for (int s = SCAN_BLK / 2; s > 0; s >>= 1) {
    if (t < s) { sc[t] += sc[t + s]; sf[t] += sf[t + s]; }
    __syncthreads();
  }
  if (t == 0) { cntPart[g] = sc[0]; expPart[g] = sf[0]; }
}

__global__ void k_scan_parts(unsigned* cntPart, float* expPart) {
  __shared__ unsigned sc[NPART];
  __shared__ float sf[NPART];
  int t = threadIdx.x;
  unsigned myc = cntPart[t];
  float myf = expPart[t];
  sc[t] = myc; sf[t] = myf;
  __syncthreads();
  for (int off = 1; off < NPART; off <<= 1) {
    unsigned c = 0; float f = 0.f;
    if (t >= off) { c = sc[t - off]; f = sf[t - off]; }
    __syncthreads();
    sc[t] += c; sf[t] += f;
    __syncthreads();
  }
  cntPart[t] = sc[t] - myc;  // exclusive prefix of reversed parts
  expPart[t] = sf[t] - myf;
}

__global__ void k_scan_final(const unsigned* __restrict__ count, const float* __restrict__ expsum,
                             const unsigned* __restrict__ cntPart, const float* __restrict__ expPart,
                             unsigned* __restrict__ sfxCnt, float* __restrict__ sfxExp) {
  __shared__ unsigned sc[SCAN_BLK];
  __shared__ float sf[SCAN_BLK];
  int t = threadIdx.x, g = blockIdx.x;
  int b = NBUCK - 1 - (g * SCAN_BLK + t);
  sc[t] = count[b];
  sf[t] = expsum[b];
  __syncthreads();
  for (int off = 1; off < SCAN_BLK; off <<= 1) {
    unsigned c = 0; float f = 0.f;
    if (t >= off) { c = sc[t - off]; f = sf[t - off]; }
    __syncthreads();
    sc[t] += c; sf[t] += f;
    __syncthreads();
  }
  sfxCnt[b] = sc[t] + cntPart[g];  // inclusive suffix: sum over buckets >= b
  sfxExp[b] = sf[t] + expPart[g];
}

__global__ void k_scatter(const float* __restrict__ yt0, const float* __restrict__ yp0, int n,
                          int rmask,
                          const unsigned* __restrict__ countTot, const unsigned* __restrict__ sfxCnt,
                          const unsigned* __restrict__ offArr, const unsigned* __restrict__ seq,
                          uint2* __restrict__ skey2, unsigned* __restrict__ sidx) {
  int i = blockIdx.x * blockDim.x + threadIdx.x;
  if (i >= n) return;
  int r = blockIdx.x & rmask;  // same mapping as k_hist (same grid/block config)
  unsigned key = __float_as_uint(yt0[2 * i]);
  unsigned b = key >> BSHIFT;
  unsigned start = sfxCnt[b] - countTot[b];  // # elements in strictly-higher buckets
  unsigned pos = start + offArr[(size_t)r * NBUCK + b] + seq[i];
  uint2 v; v.x = key; v.y = __float_as_uint(expf(yp0[i]));
  skey2[pos] = v;
  sidx[pos] = i;
}

__global__ void k_main(const float* __restrict__ yt0, const float* __restrict__ yp0,
                       const float* __restrict__ yp1, const int* __restrict__ Hj,
                       int n, int m,
                       const unsigned* __restrict__ countTot, const float* __restrict__ expTot,
                       const unsigned* __restrict__ sfxCnt, const float* __restrict__ sfxExp,
                       const uint2* __restrict__ skey2, const unsigned* __restrict__ sidx,
                       float* __restrict__ xh, double* __restrict__ accum) {
  int p = blockIdx.x * blockDim.x + threadIdx.x;
  int lane = threadIdx.x & 63;
  bool act = (p < n);
  unsigned key = 0, idx = 0, b = 0;
  unsigned start = 0xFFFFFFFFu, end = 0;  // neutral for min/max when inactive
  float e = 0.f;
  if (act) {
    uint2 kv = skey2[p];
    key = kv.x;
    e = __uint_as_float(kv.y);
    idx = sidx[p];
    b = key >> BSHIFT;
    end = sfxCnt[b];
    start = end - countTot[b];
    // defensive clamps: corrupt bounds can never cause runaway loops
    if (end > (unsigned)n) end = (unsigned)n;
    if (start > end) start = end;
  }
  // wave union window [wlo, whi) via shuffle butterfly (deterministic, in-wave)
  unsigned wlo = start, whi = end;
  #pragma unroll
  for (int d = 32; d > 0; d >>= 1) {
    unsigned a = __shfl_xor(wlo, d, 64);
    unsigned c = __shfl_xor(whi, d, 64);
    wlo = (a < wlo) ? a : wlo;
    whi = (c > whi) ? c : whi;
  }

  float wsum = 0.f;
  unsigned wcnt = 0, weq = 0;
  for (unsigned qb = wlo; qb < whi; qb += 64) {
    unsigned q = qb + (unsigned)lane;
    uint2 v;
    if (q < whi) v = skey2[q];       // coalesced: lane i -> element qb+i
    else { v.x = 0u; v.y = 0u; }
    #pragma unroll 16
    for (int k = 0; k < 64; ++k) {
      unsigned vx = __shfl(v.x, k, 64);   // loop-uniform lane -> readlane (SGPR bcast)
      unsigned vy = __shfl(v.y, k, 64);
      unsigned q2 = qb + (unsigned)k;
      bool in = (q2 >= start) & (q2 < end);   // restrict to this lane's bucket
      bool gt = in & (vx > key);
      wsum += gt ? __uint_as_float(vy) : 0.f;
      wcnt += gt ? 1u : 0u;
      weq  += (in & (vx == key)) ? 1u : 0u;
    }
  }

  double contrib = 0.0;
  if (act) {
    if (weq > 1) {  // rare: exact-key tie with another element -> idx order
      for (unsigned q = start; q < end; ++q) {
        uint2 v = skey2[q];
        if (v.x == key && sidx[q] < idx) { wsum += __uint_as_float(v.y); wcnt++; }
      }
    }
    // denom = exp-sum of all elements strictly before p in descending-time order, + self
    float denom = (sfxExp[b] - expTot[b]) + wsum + e;
    int rank = (int)(start + wcnt);
    float ev = yt0[2 * idx + 1];
    float xb0 = yp0[idx];
    contrib = (double)(ev * (logf(denom) - xb0));  // lossA element
    // scatter y_pred1 to ordinal anchor slots whose sorted position == rank
    int lo = 0, hi = m;
    while (lo < hi) { int mid = (lo + hi) >> 1; if (Hj[mid] < rank) lo = mid + 1; else hi = mid; }
    if (lo < m && Hj[lo] == rank) {
      float xb1 = yp1[idx];
      for (int j = lo; j < m && Hj[j] == rank; ++j) xh[j] = xb1;
    }
  }
  __shared__ double red[256];
  int t = threadIdx.x;
  red[t] = contrib;
  __syncthreads();
  for (int s = 128; s > 0; s >>= 1) {
    if (t < s) red[t] += red[t + s];
    __syncthreads();
  }
  if (t == 0) atomicAdd(accum, red[0]);
}

// cost2 = M(M+1)/2 - sum_j exp(xh_j) * S_j,  S_j = inclusive suffix sum of exp(-xh).
// Wave-shuffle suffix scan: 8 elem/thread, 6 shfl steps/wave, 16 wave totals via
// LDS, 2 syncs per 8192-element pass.
__global__ void k_final(const float* __restrict__ xh, int m,
                        const double* __restrict__ accum, const float* __restrict__ log_vars,
                        int n, float* __restrict__ out) {
  __shared__ float wtots[16];
  __shared__ double dred[1024];
  int t = threadIdx.x;
  int lane = t & 63;
  int w = t >> 6;
  double acc = 0.0;
  float carry = 0.f;
  int passes = (m + 8191) / 8192;
  for (int pss = passes - 1; pss >= 0; --pss) {
    int base = pss * 8192 + t * 8;
    float x[8], eb[8];
    float c = 0.f;
    #pragma unroll
    for (int k = 0; k < 8; ++k) {
      int j = base + k;
      x[k] = (j < m) ? xh[j] : 0.f;
      eb[k] = (j < m) ? expf(-x[k]) : 0.f;
      c += eb[k];
    }
    // inclusive suffix scan of per-thread chunk sums within the wave
    float s = c;
    #pragma unroll
    for (int d = 1; d < 64; d <<= 1) {
      float o = __shfl_down(s, d, 64);
      if (lane + d < 64) s += o;
    }
    float wtot = __shfl(s, 0, 64);   // wave total (lane 0 holds full suffix)
    if (lane == 0) wtots[w] = wtot;
    __syncthreads();
    float after = 0.f;
    #pragma unroll
    for (int w2 = 0; w2 < 16; ++w2) if (w2 > w) after += wtots[w2];
    float ptot = 0.f;
    #pragma unroll
    for (int w2 = 0; w2 < 16; ++w2) ptot += wtots[w2];
    float S = (s - c) + after + carry;
    #pragma unroll
    for (int k = 7; k >= 0; --k) {
      int j = base + k;
      S += eb[k];
      if (j < m) acc += (double)(expf(x[k]) * S);
    }
    __syncthreads();   // protect wtots before next pass overwrites
    carry += ptot;
  }
  dred[t] = acc;
  __syncthreads();
  for (int s2 = 512; s2 > 0; s2 >>= 1) {
    if (t < s2) dred[t] += dred[t + s2];
    __syncthreads();
  }
  if (t == 0) {
    double T = (double)m * (double)(m + 1) * 0.5;
    double cost2 = T - dred[0];
    float lv0 = log_vars[0], lv1 = log_vars[1];
    float prec1 = fminf(expf(-lv1), 1.0f);  // clip(exp(-lv1),0,1)
    double loss = *accum + (double)n * (double)lv0 + (double)prec1 * cost2 + (double)lv1;
    out[0] = (float)loss;
  }
}

extern "C" void kernel_launch(void* const* d_in, const int* in_sizes, int n_in,
                              void* d_out, int out_size, void* d_ws, size_t ws_size,
                              hipStream_t stream) {
  const float* yt0 = (const float*)d_in[0];
  const float* yp0 = (const float*)d_in[2];
  const float* yp1 = (const float*)d_in[3];
  const int*   Hj  = (const int*)d_in[4];
  const float* lv  = (const float*)d_in[5];
  int n = in_sizes[0] / 2;  // y_true0 is [N,2]
  int m = in_sizes[4];

  // Replica count: 8 if workspace fits (~19 MB), else 1 (~7 MB).
  int nrep = RMAX;
  {
    size_t need = (size_t)nrep * NBUCK * 4 * 3   // count, expsum, offArr
                + (size_t)NBUCK * 4 * 4          // countTot, expTot, sfxCnt, sfxExp
                + (size_t)NPART * 4 * 2
                + (size_t)n * 4 * 4              // seq, skey2 (8B), sidx
                + (size_t)m * 4 + 256;
    if (ws_size < need) nrep = 1;
  }
  int rmask = nrep - 1;

  char* ws = (char*)d_ws;
  size_t off = 0;
  unsigned* count  = (unsigned*)(ws + off); off += (size_t)nrep * NBUCK * 4;
  float*    expsum = (float*)(ws + off);    off += (size_t)nrep * NBUCK * 4;
  double*   accum  = (double*)(ws + off);   off += 16;
  size_t zbytes = off;  // everything above must start zeroed
  unsigned* offArr  = (unsigned*)(ws + off); off += (size_t)nrep * NBUCK * 4;
  unsigned* countTot= (unsigned*)(ws + off); off += (size_t)NBUCK * 4;
  float*    expTot  = (float*)(ws + off);    off += (size_t)NBUCK * 4;
  unsigned* cntPart = (unsigned*)(ws + off); off += (size_t)NPART * 4;
  float*    expPart = (float*)(ws + off);    off += (size_t)NPART * 4;
  unsigned* sfxCnt  = (unsigned*)(ws + off); off += (size_t)NBUCK * 4;
  float*    sfxExp  = (float*)(ws + off);    off += (size_t)NBUCK * 4;
  unsigned* seq     = (unsigned*)(ws + off); off += (size_t)n * 4;
  uint2*    skey2   = (uint2*)(ws + off);    off += (size_t)n * 8;   // 8-aligned
  unsigned* sidx    = (unsigned*)(ws + off); off += (size_t)n * 4;
  float*    xh      = (float*)(ws + off);    off += (size_t)m * 4;

  hipMemsetAsync(d_ws, 0, zbytes, stream);

  int blk = 256;
  int g_n = (n + blk - 1) / blk;
  k_hist<<<g_n, blk, 0, stream>>>(yt0, yp0, n, rmask, count, expsum, seq);
  k_scan_reduce<<<NPART, SCAN_BLK, 0, stream>>>(count, expsum, nrep,
                                                countTot, expTot, offArr, cntPart, expPart);
  k_scan_parts<<<1, NPART, 0, stream>>>(cntPart, expPart);
  k_scan_final<<<NPART, SCAN_BLK, 0, stream>>>(countTot, expTot, cntPart, expPart, sfxCnt, sfxExp);
  k_scatter<<<g_n, blk, 0, stream>>>(yt0, yp0, n, rmask, countTot, sfxCnt, offArr, seq,
                                     skey2, sidx);
  k_main<<<g_n, blk, 0, stream>>>(yt0, yp0, yp1, Hj, n, m, countTot, expTot, sfxCnt, sfxExp,
                                  skey2, sidx, xh, accum);
  k_final<<<1, 1024, 0, stream>>>(xh, m, accum, lv, n, (float*)d_out);
}

// Round 8
// 152.305 us; speedup vs baseline: 1.2678x; 1.2678x over previous
//
#include <hip/hip_runtime.h>
#include <math.h>

// Bucketed rank/cumsum (round 8): round-6 pipeline (fused scan+reduce, shuffle
// k_final — green) + round-5 k_main (8x uint2 batched per-lane scan — green,
// best measured) + BSHIFT 14->13 (compile-time only: halves dense-octave
// bucket occupancy g, halving k_main scan work and k_hist atomic contention).
// Round-7 lesson: __shfl with non-constant lane = ds_bpermute (2 LDS ops per
// element) — wave-broadcast scan is a regression; per-lane L1-hit loads win.
//   key = float bits of time (positive floats order monotonically).
//   bucket = key >> 13 -> 2^18 buckets covers every positive float.
//   k_hist: R=8 replicas -> ~16-way same-address contention; seq[i] = atomicAdd
//     return = slot within (r,bucket). Suffix scans over buckets give
//     (count above, exp-sum above); within-bucket order resolved exactly in
//     k_main (order-invariant). Tie-break (key desc, idx asc) = top_k stability.

#define BSHIFT 13
#define NBUCK (1 << 18)           // 262144; max positive-float key>>13 = 260095
#define SCAN_BLK 1024
#define NPART (NBUCK / SCAN_BLK)  // 256
#define RMAX 8

__global__ void k_hist(const float* __restrict__ yt0, const float* __restrict__ yp0,
                       int n, int rmask,
                       unsigned* __restrict__ count, float* __restrict__ expsum,
                       unsigned* __restrict__ seq) {
  int i = blockIdx.x * blockDim.x + threadIdx.x;
  if (i >= n) return;
  int r = blockIdx.x & rmask;
  unsigned key = __float_as_uint(yt0[2 * i]);
  unsigned b = key >> BSHIFT;
  seq[i] = atomicAdd(&count[(size_t)r * NBUCK + b], 1u);
  atomicAdd(&expsum[(size_t)r * NBUCK + b], expf(yp0[i]));
}

// Fold replicas (countTot/expTot/offArr) AND produce per-part suffix partials.
__global__ void k_scan_reduce(const unsigned* __restrict__ count, const float* __restrict__ expsum,
                              int nrep,
                              unsigned* __restrict__ countTot, float* __restrict__ expTot,
                              unsigned* __restrict__ offArr,
                              unsigned* __restrict__ cntPart, float* __restrict__ expPart) {
  __shared__ unsigned sc[SCAN_BLK];
  __shared__ float sf[SCAN_BLK];
  int t = threadIdx.x, g = blockIdx.x;
  int b = NBUCK - 1 - (g * SCAN_BLK + t);  // reversed order -> suffix scan
  unsigned tot = 0;
  float ftot = 0.f;
  for (int r = 0; r < nrep; ++r) {
    offArr[(size_t)r * NBUCK + b] = tot;
    tot += count[(size_t)r * NBUCK + b];
    ftot += expsum[(size_t)r * NBUCK + b];
  }
  countTot[b] = tot;
  expTot[b] = ftot;
  sc[t] = tot;
  sf[t] = ftot;
  __syncthreads();
  for (int s = SCAN_BLK / 2; s > 0; s >>= 1) {
    if (t < s) { sc[t] += sc[t + s]; sf[t] += sf[t + s]; }
    __syncthreads();
  }
  if (t == 0) { cntPart[g] = sc[0]; expPart[g] = sf[0]; }
}

__global__ void k_scan_parts(unsigned* cntPart, float* expPart) {
  __shared__ unsigned sc[NPART];
  __shared__ float sf[NPART];
  int t = threadIdx.x;
  unsigned myc = cntPart[t];
  float myf = expPart[t];
  sc[t] = myc; sf[t] = myf;
  __syncthreads();
  for (int off = 1; off < NPART; off <<= 1) {
    unsigned c = 0; float f = 0.f;
    if (t >= off) { c = sc[t - off]; f = sf[t - off]; }
    __syncthreads();
    sc[t] += c; sf[t] += f;
    __syncthreads();
  }
  cntPart[t] = sc[t] - myc;  // exclusive prefix of reversed parts
  expPart[t] = sf[t] - myf;
}

__global__ void k_scan_final(const unsigned* __restrict__ count, const float* __restrict__ expsum,
                             const unsigned* __restrict__ cntPart, const float* __restrict__ expPart,
                             unsigned* __restrict__ sfxCnt, float* __restrict__ sfxExp) {
  __shared__ unsigned sc[SCAN_BLK];
  __shared__ float sf[SCAN_BLK];
  int t = threadIdx.x, g = blockIdx.x;
  int b = NBUCK - 1 - (g * SCAN_BLK + t);
  sc[t] = count[b];
  sf[t] = expsum[b];
  __syncthreads();
  for (int off = 1; off < SCAN_BLK; off <<= 1) {
    unsigned c = 0; float f = 0.f;
    if (t >= off) { c = sc[t - off]; f = sf[t - off]; }
    __syncthreads();
    sc[t] += c; sf[t] += f;
    __syncthreads();
  }
  sfxCnt[b] = sc[t] + cntPart[g];  // inclusive suffix: sum over buckets >= b
  sfxExp[b] = sf[t] + expPart[g];
}

__global__ void k_scatter(const float* __restrict__ yt0, const float* __restrict__ yp0, int n,
                          int rmask,
                          const unsigned* __restrict__ countTot, const unsigned* __restrict__ sfxCnt,
                          const unsigned* __restrict__ offArr, const unsigned* __restrict__ seq,
                          uint2* __restrict__ skey2, unsigned* __restrict__ sidx) {
  int i = blockIdx.x * blockDim.x + threadIdx.x;
  if (i >= n) return;
  int r = blockIdx.x & rmask;  // same mapping as k_hist (same grid/block config)
  unsigned key = __float_as_uint(yt0[2 * i]);
  unsigned b = key >> BSHIFT;
  unsigned start = sfxCnt[b] - countTot[b];  // # elements in strictly-higher buckets
  unsigned pos = start + offArr[(size_t)r * NBUCK + b] + seq[i];
  uint2 v; v.x = key; v.y = __float_as_uint(expf(yp0[i]));
  skey2[pos] = v;
  sidx[pos] = i;
}

__global__ void k_main(const float* __restrict__ yt0, const float* __restrict__ yp0,
                       const float* __restrict__ yp1, const int* __restrict__ Hj,
                       int n, int m,
                       const unsigned* __restrict__ countTot, const float* __restrict__ expTot,
                       const unsigned* __restrict__ sfxCnt, const float* __restrict__ sfxExp,
                       const uint2* __restrict__ skey2, const unsigned* __restrict__ sidx,
                       float* __restrict__ xh, double* __restrict__ accum) {
  int p = blockIdx.x * blockDim.x + threadIdx.x;
  double contrib = 0.0;
  if (p < n) {
    uint2 kv = skey2[p];
    unsigned key = kv.x;
    float e = __uint_as_float(kv.y);
    unsigned idx = sidx[p];
    unsigned b = key >> BSHIFT;
    unsigned end = sfxCnt[b];
    unsigned start = end - countTot[b];
    // defensive clamps: corrupt bounds can never cause runaway loops
    if (end > (unsigned)n) end = (unsigned)n;
    if (start > end) start = end;
    float wsum = 0.f;
    unsigned wcnt = 0;
    unsigned q = start;
    // 8x unrolled batched loads: 8 independent uint2 loads per iteration (MLP);
    // sidx loaded only on exact-key tie (rare).
    while (q + 8 <= end) {
      uint2 v[8];
      #pragma unroll
      for (int k = 0; k < 8; ++k) v[k] = skey2[q + k];
      #pragma unroll
      for (int k = 0; k < 8; ++k) {
        if (v[k].x > key) { wsum += __uint_as_float(v[k].y); wcnt++; }
        else if (v[k].x == key && sidx[q + k] < idx) { wsum += __uint_as_float(v[k].y); wcnt++; }
      }
      q += 8;
    }
    for (; q < end; ++q) {
      uint2 v = skey2[q];
      if (v.x > key) { wsum += __uint_as_float(v.y); wcnt++; }
      else if (v.x == key && sidx[q] < idx) { wsum += __uint_as_float(v.y); wcnt++; }
    }
    // denom = exp-sum of all elements strictly before p in descending-time order, + self
    float denom = (sfxExp[b] - expTot[b]) + wsum + e;
    int rank = (int)(start + wcnt);
    float ev = yt0[2 * idx + 1];
    float xb0 = yp0[idx];
    contrib = (double)(ev * (logf(denom) - xb0));  // lossA element
    // scatter y_pred1 to ordinal anchor slots whose sorted position == rank
    int lo = 0, hi = m;
    while (lo < hi) { int mid = (lo + hi) >> 1; if (Hj[mid] < rank) lo = mid + 1; else hi = mid; }
    if (lo < m && Hj[lo] == rank) {
      float xb1 = yp1[idx];
      for (int j = lo; j < m && Hj[j] == rank; ++j) xh[j] = xb1;
    }
  }
  __shared__ double red[256];
  int t = threadIdx.x;
  red[t] = contrib;
  __syncthreads();
  for (int s = 128; s > 0; s >>= 1) {
    if (t < s) red[t] += red[t + s];
    __syncthreads();
  }
  if (t == 0) atomicAdd(accum, red[0]);
}

// cost2 = M(M+1)/2 - sum_j exp(xh_j) * S_j,  S_j = inclusive suffix sum of exp(-xh).
// Wave-shuffle suffix scan: 8 elem/thread, 6 shfl steps/wave, 16 wave totals via
// LDS, 2 syncs per 8192-element pass.
__global__ void k_final(const float* __restrict__ xh, int m,
                        const double* __restrict__ accum, const float* __restrict__ log_vars,
                        int n, float* __restrict__ out) {
  __shared__ float wtots[16];
  __shared__ double dred[1024];
  int t = threadIdx.x;
  int lane = t & 63;
  int w = t >> 6;
  double acc = 0.0;
  float carry = 0.f;
  int passes = (m + 8191) / 8192;
  for (int pss = passes - 1; pss >= 0; --pss) {
    int base = pss * 8192 + t * 8;
    float x[8], eb[8];
    float c = 0.f;
    #pragma unroll
    for (int k = 0; k < 8; ++k) {
      int j = base + k;
      x[k] = (j < m) ? xh[j] : 0.f;
      eb[k] = (j < m) ? expf(-x[k]) : 0.f;
      c += eb[k];
    }
    // inclusive suffix scan of per-thread chunk sums within the wave
    float s = c;
    #pragma unroll
    for (int d = 1; d < 64; d <<= 1) {
      float o = __shfl_down(s, d, 64);
      if (lane + d < 64) s += o;
    }
    float wtot = __shfl(s, 0, 64);   // wave total (lane 0 holds full suffix)
    if (lane == 0) wtots[w] = wtot;
    __syncthreads();
    float after = 0.f;
    #pragma unroll
    for (int w2 = 0; w2 < 16; ++w2) if (w2 > w) after += wtots[w2];
    float ptot = 0.f;
    #pragma unroll
    for (int w2 = 0; w2 < 16; ++w2) ptot += wtots[w2];
    float S = (s - c) + after + carry;
    #pragma unroll
    for (int k = 7; k >= 0; --k) {
      int j = base + k;
      S += eb[k];
      if (j < m) acc += (double)(expf(x[k]) * S);
    }
    __syncthreads();   // protect wtots before next pass overwrites
    carry += ptot;
  }
  dred[t] = acc;
  __syncthreads();
  for (int s2 = 512; s2 > 0; s2 >>= 1) {
    if (t < s2) dred[t] += dred[t + s2];
    __syncthreads();
  }
  if (t == 0) {
    double T = (double)m * (double)(m + 1) * 0.5;
    double cost2 = T - dred[0];
    float lv0 = log_vars[0], lv1 = log_vars[1];
    float prec1 = fminf(expf(-lv1), 1.0f);  // clip(exp(-lv1),0,1)
    double loss = *accum + (double)n * (double)lv0 + (double)prec1 * cost2 + (double)lv1;
    out[0] = (float)loss;
  }
}

extern "C" void kernel_launch(void* const* d_in, const int* in_sizes, int n_in,
                              void* d_out, int out_size, void* d_ws, size_t ws_size,
                              hipStream_t stream) {
  const float* yt0 = (const float*)d_in[0];
  const float* yp0 = (const float*)d_in[2];
  const float* yp1 = (const float*)d_in[3];
  const int*   Hj  = (const int*)d_in[4];
  const float* lv  = (const float*)d_in[5];
  int n = in_sizes[0] / 2;  // y_true0 is [N,2]
  int m = in_sizes[4];

  // Replica count: 8 if workspace fits (~29 MB at NBUCK=2^18), else 1.
  int nrep = RMAX;
  {
    size_t need = (size_t)nrep * NBUCK * 4 * 3   // count, expsum, offArr
                + (size_t)NBUCK * 4 * 4          // countTot, expTot, sfxCnt, sfxExp
                + (size_t)NPART * 4 * 2
                + (size_t)n * 4 * 4              // seq, skey2 (8B), sidx
                + (size_t)m * 4 + 256;
    if (ws_size < need) nrep = 1;
  }
  int rmask = nrep - 1;

  char* ws = (char*)d_ws;
  size_t off = 0;
  unsigned* count  = (unsigned*)(ws + off); off += (size_t)nrep * NBUCK * 4;
  float*    expsum = (float*)(ws + off);    off += (size_t)nrep * NBUCK * 4;
  double*   accum  = (double*)(ws + off);   off += 16;
  size_t zbytes = off;  // everything above must start zeroed
  unsigned* offArr  = (unsigned*)(ws + off); off += (size_t)nrep * NBUCK * 4;
  unsigned* countTot= (unsigned*)(ws + off); off += (size_t)NBUCK * 4;
  float*    expTot  = (float*)(ws + off);    off += (size_t)NBUCK * 4;
  unsigned* cntPart = (unsigned*)(ws + off); off += (size_t)NPART * 4;
  float*    expPart = (float*)(ws + off);    off += (size_t)NPART * 4;
  unsigned* sfxCnt  = (unsigned*)(ws + off); off += (size_t)NBUCK * 4;
  float*    sfxExp  = (float*)(ws + off);    off += (size_t)NBUCK * 4;
  unsigned* seq     = (unsigned*)(ws + off); off += (size_t)n * 4;
  uint2*    skey2   = (uint2*)(ws + off);    off += (size_t)n * 8;   // 8-aligned
  unsigned* sidx    = (unsigned*)(ws + off); off += (size_t)n * 4;
  float*    xh      = (float*)(ws + off);    off += (size_t)m * 4;

  hipMemsetAsync(d_ws, 0, zbytes, stream);

  int blk = 256;
  int g_n = (n + blk - 1) / blk;
  k_hist<<<g_n, blk, 0, stream>>>(yt0, yp0, n, rmask, count, expsum, seq);
  k_scan_reduce<<<NPART, SCAN_BLK, 0, stream>>>(count, expsum, nrep,
                                                countTot, expTot, offArr, cntPart, expPart);
  k_scan_parts<<<1, NPART, 0, stream>>>(cntPart, expPart);
  k_scan_final<<<NPART, SCAN_BLK, 0, stream>>>(countTot, expTot, cntPart, expPart, sfxCnt, sfxExp);
  k_scatter<<<g_n, blk, 0, stream>>>(yt0, yp0, n, rmask, countTot, sfxCnt, offArr, seq,
                                     skey2, sidx);
  k_main<<<g_n, blk, 0, stream>>>(yt0, yp0, yp1, Hj, n, m, countTot, expTot, sfxCnt, sfxExp,
                                  skey2, sidx, xh, accum);
  k_final<<<1, 1024, 0, stream>>>(xh, m, accum, lv, n, (float*)d_out);
}